// Round 4
// baseline (99.279 us; speedup 1.0000x reference)
//
#include <hip/hip_runtime.h>
#include <math.h>

#define NCLS 30
#define OBJ_BLOCKS 132        // ceil(33600 float4 / 256)
#define POS_BLOCKS 12         // 12 blocks x 4 waves = 48 (scale,batch) tasks
#define NTASK 48
#define TOTAL_BLOCKS (OBJ_BLOCKS + POS_BLOCKS)
#define NSLOT (OBJ_BLOCKS + NTASK)   // 180 published slots
#define MAGIC 0x13579BDFu

// ws layout: slot s = ws[s*8 .. s*8+7] (32 B/slot, 180 slots, no init needed):
//   obj block i  -> slot i        : {sum_sp_s0, sum_sp_s1, sum_sp_s2, -, ..., flag}
//   pos task  t  -> slot 132 + t  : {ce_sum, sl1_sum, npos, pos_obj_sum, ..., flag}
// flag = unsigned word 7 of the slot, published with agent-scope release.
// A dedicated finalizer block (bx == TOTAL_BLOCKS) spin-polls all flags,
// reduces, and writes out[0..3]. No memset / second kernel needed.

__device__ __forceinline__ float softplusf(float x) {
    return (x > 20.0f) ? x : log1pf(__expf(x));
}

__device__ __forceinline__ void st_rel_f(float* p, float v) {
    __hip_atomic_store(p, v, __ATOMIC_RELAXED, __HIP_MEMORY_SCOPE_AGENT);
}
__device__ __forceinline__ void publish(unsigned* f) {
    __hip_atomic_store(f, MAGIC, __ATOMIC_RELEASE, __HIP_MEMORY_SCOPE_AGENT);
}

__global__ __launch_bounds__(256) void detloss_fused(
    const float* __restrict__ cls0, const float* __restrict__ reg0, const float* __restrict__ obj0,
    const float* __restrict__ cls1, const float* __restrict__ reg1, const float* __restrict__ obj1,
    const float* __restrict__ cls2, const float* __restrict__ reg2, const float* __restrict__ obj2,
    const float* __restrict__ boxes, const int* __restrict__ labels,
    float* __restrict__ ws, float* __restrict__ out)
{
    const int bx = blockIdx.x;
    const int tid = threadIdx.x;
    const int wave = tid >> 6;
    const int lane = tid & 63;
    unsigned* wsu = (unsigned*)ws;

    if (bx < OBJ_BLOCKS) {
        // ---- softplus(obj) reduction, float4-vectorized, shfl tree-reduced ----
        float a0 = 0.0f, a1 = 0.0f, a2 = 0.0f;
        const int gi = bx * 256 + tid;  // global float4 index, 33600 total
        if (gi < 33600) {
            const float4* p; int li;
            if (gi < 25600)      { p = (const float4*)obj0; li = gi; }
            else if (gi < 32000) { p = (const float4*)obj1; li = gi - 25600; }
            else                 { p = (const float4*)obj2; li = gi - 32000; }
            const float4 v = p[li];
            const float s = softplusf(v.x) + softplusf(v.y) + softplusf(v.z) + softplusf(v.w);
            if (gi < 25600) a0 = s; else if (gi < 32000) a1 = s; else a2 = s;
        }
        #pragma unroll
        for (int m = 32; m > 0; m >>= 1) {
            a0 += __shfl_xor(a0, m);
            a1 += __shfl_xor(a1, m);
            a2 += __shfl_xor(a2, m);
        }
        __shared__ float red[4][3];
        if (lane == 0) { red[wave][0] = a0; red[wave][1] = a1; red[wave][2] = a2; }
        __syncthreads();
        if (tid == 0) {
            float* o = ws + (size_t)bx * 8;
            st_rel_f(&o[0], red[0][0] + red[1][0] + red[2][0] + red[3][0]);
            st_rel_f(&o[1], red[0][1] + red[1][1] + red[2][1] + red[3][1]);
            st_rel_f(&o[2], red[0][2] + red[1][2] + red[2][2] + red[3][2]);
            publish(&wsu[bx * 8 + 7]);
        }
    } else if (bx < TOTAL_BLOCKS) {
        // ---- positive-cell losses: one wave per (scale,batch), one lane per box ----
        const int task  = (bx - OBJ_BLOCKS) * 4 + wave;  // 0..47
        const int scale = task >> 4;
        const int batch = task & 15;
        const float* cls; const float* reg; const float* obj; int H, W;
        if (scale == 0)      { cls = cls0; reg = reg0; obj = obj0; H = 80; W = 80; }
        else if (scale == 1) { cls = cls1; reg = reg1; obj = obj1; H = 40; W = 40; }
        else                 { cls = cls2; reg = reg2; obj = obj2; H = 20; W = 20; }
        const int HW = H * W;

        const int j = batch * 64 + lane;                 // global box id
        const float4 bv = ((const float4*)boxes)[j];     // cx,cy,w,h
        const int lab = labels[j];
        int gx = (int)(bv.x * (float)W); gx = max(0, min(W - 1, gx));
        int gy = (int)(bv.y * (float)H); gy = max(0, min(H - 1, gy));
        const int cell = gy * W + gx;

        // winner = no later box (same batch) maps to same cell (scatter last-write-wins)
        // minlab = min label among boxes sharing the cell (argmax ties -> lowest idx)
        bool winner = true;
        int minlab = 1 << 30;
        for (int m = 0; m < 64; ++m) {
            const int oc = __shfl(cell, m);
            const int ol = __shfl(lab, m);
            if (oc == cell) {
                if (m > lane) winner = false;
                minlab = min(minlab, ol);
            }
        }

        float ce = 0.0f, sl = 0.0f, npos = 0.0f, po = 0.0f;
        if (winner) {
            // cross-entropy via 30 strided logits kept in registers (static unroll)
            const float* cb = cls + (size_t)batch * NCLS * HW + cell;
            float v[NCLS];
            float mx = -INFINITY;
            #pragma unroll
            for (int c = 0; c < NCLS; ++c) { v[c] = cb[(size_t)c * HW]; mx = fmaxf(mx, v[c]); }
            float se = 0.0f, tgt = 0.0f;
            #pragma unroll
            for (int c = 0; c < NCLS; ++c) {
                se += __expf(v[c] - mx);
                if (c == minlab) tgt = v[c];   // cndmask, minlab known pre-gather
            }
            ce = mx + __logf(se) - tgt;

            // smooth-L1 (beta=1) vs own box (last-write target), mean/4, clamp 10
            const float* rb = reg + (size_t)batch * 4 * HW + cell;
            const float t[4] = { bv.x, bv.y, bv.z, bv.w };
            #pragma unroll
            for (int k = 0; k < 4; ++k) {
                const float d = fabsf(rb[(size_t)k * HW] - t[k]);
                sl += (d < 1.0f) ? 0.5f * d * d : (d - 0.5f);
            }
            sl = fminf(sl * 0.25f, 10.0f);

            po = obj[(size_t)batch * HW + cell];
            npos = 1.0f;
        }
        #pragma unroll
        for (int m = 32; m > 0; m >>= 1) {
            ce   += __shfl_xor(ce, m);
            sl   += __shfl_xor(sl, m);
            npos += __shfl_xor(npos, m);
            po   += __shfl_xor(po, m);
        }
        if (lane == 0) {
            const int slot = OBJ_BLOCKS + task;
            float* o = ws + (size_t)slot * 8;
            st_rel_f(&o[0], ce);
            st_rel_f(&o[1], sl);
            st_rel_f(&o[2], npos);
            st_rel_f(&o[3], po);
            publish(&wsu[slot * 8 + 7]);
        }
    } else if (wave == 0) {
        // ---- finalizer block: spin on 180 flags (3 per lane), reduce, write out ----
        const int s0 = lane, s1 = lane + 64, s2 = lane + 128;
        bool d0 = false, d1 = false, d2 = (s2 >= NSLOT);
        for (;;) {
            if (!d0) d0 = (__hip_atomic_load(&wsu[s0 * 8 + 7], __ATOMIC_ACQUIRE, __HIP_MEMORY_SCOPE_AGENT) == MAGIC);
            if (!d1) d1 = (__hip_atomic_load(&wsu[s1 * 8 + 7], __ATOMIC_ACQUIRE, __HIP_MEMORY_SCOPE_AGENT) == MAGIC);
            if (!d2) d2 = (__hip_atomic_load(&wsu[s2 * 8 + 7], __ATOMIC_ACQUIRE, __HIP_MEMORY_SCOPE_AGENT) == MAGIC);
            if (__all(d0 && d1 && d2)) break;
        }
        // accumulate this lane's slots: 15 = 3 scales x {softplus} + 3 x {ce,sl,npos,po}
        float acc[15];
        #pragma unroll
        for (int k = 0; k < 15; ++k) acc[k] = 0.0f;
        const int slots[3] = { s0, s1, s2 };
        for (int q = 0; q < 3; ++q) {
            const int s = slots[q];
            if (s >= NSLOT) continue;
            const float* p = ws + (size_t)s * 8;
            if (s < OBJ_BLOCKS) {
                acc[0] += __hip_atomic_load(&p[0], __ATOMIC_RELAXED, __HIP_MEMORY_SCOPE_AGENT);
                acc[1] += __hip_atomic_load(&p[1], __ATOMIC_RELAXED, __HIP_MEMORY_SCOPE_AGENT);
                acc[2] += __hip_atomic_load(&p[2], __ATOMIC_RELAXED, __HIP_MEMORY_SCOPE_AGENT);
            } else {
                const int t = s - OBJ_BLOCKS;
                const int sc = t >> 4;
                #pragma unroll
                for (int k = 0; k < 4; ++k)
                    acc[3 + sc * 4 + k] += __hip_atomic_load(&p[k], __ATOMIC_RELAXED, __HIP_MEMORY_SCOPE_AGENT);
            }
        }
        #pragma unroll
        for (int m = 32; m > 0; m >>= 1)
            #pragma unroll
            for (int k = 0; k < 15; ++k) acc[k] += __shfl_xor(acc[k], m);

        if (lane == 0) {
            const float Ms[3] = { 16.0f * 6400.0f, 16.0f * 1600.0f, 16.0f * 400.0f };
            float clsl = 0.0f, regl = 0.0f, objl = 0.0f;
            #pragma unroll
            for (int s = 0; s < 3; ++s) {
                const float npos = fmaxf(acc[3 + s * 4 + 2], 1.0f);
                clsl += acc[3 + s * 4 + 0] / npos;            // CLS_W = 1
                regl += 5.0f * acc[3 + s * 4 + 1] / npos;     // REG_W = 5
                objl += (acc[s] - acc[3 + s * 4 + 3]) / Ms[s]; // OBJ_W = 1
            }
            clsl /= 3.0f; regl /= 3.0f; objl /= 3.0f;
            out[0] = clsl + regl + objl;
            out[1] = clsl;
            out[2] = regl;
            out[3] = objl;
        }
    }
}

extern "C" void kernel_launch(void* const* d_in, const int* in_sizes, int n_in,
                              void* d_out, int out_size, void* d_ws, size_t ws_size,
                              hipStream_t stream) {
    const float* cls0   = (const float*)d_in[0];
    const float* reg0   = (const float*)d_in[1];
    const float* obj0   = (const float*)d_in[2];
    const float* obj0_  = obj0; (void)obj0_;
    const float* cls1   = (const float*)d_in[3];
    const float* reg1   = (const float*)d_in[4];
    const float* obj1   = (const float*)d_in[5];
    const float* cls2   = (const float*)d_in[6];
    const float* reg2   = (const float*)d_in[7];
    const float* obj2   = (const float*)d_in[8];
    const float* boxes  = (const float*)d_in[9];
    const int*   labels = (const int*)d_in[10];
    float* ws  = (float*)d_ws;
    float* out = (float*)d_out;

    // single kernel node, no memset: slots are published via sentinel flags,
    // so no pre-zeroed workspace state is required.
    detloss_fused<<<dim3(TOTAL_BLOCKS + 1), 256, 0, stream>>>(
        cls0, reg0, obj0, cls1, reg1, obj1, cls2, reg2, obj2,
        boxes, labels, ws, out);
}

// Round 5
// 97.893 us; speedup vs baseline: 1.0142x; 1.0142x over previous
//
#include <hip/hip_runtime.h>
#include <math.h>

#define NCLS 30
#define OBJ_BLOCKS 132        // ceil(33600 float4 / 256)
#define POS_BLOCKS 12         // 12 blocks x 4 waves = 48 (scale,batch) tasks
#define TOTAL_BLOCKS (OBJ_BLOCKS + POS_BLOCKS)

// ws layout:
//   float ws[s*5 + 0] = sum softplus(obj) over all cells   (scale s)
//   float ws[s*5 + 1] = sum ce over positive cells
//   float ws[s*5 + 2] = sum smoothL1 over positive cells
//   float ws[s*5 + 3] = npos
//   float ws[s*5 + 4] = sum obj logits over positive cells
//   ((unsigned*)ws)[15] = done-block counter
// All zeroed by a 64 B memset node before the kernel.
//
// Structure note (R4 post-mortem): last-block-done beats a dedicated
// spin-poll finalizer block (96.5 vs 99.3 us) — the last producer reduces
// immediately instead of paying cross-XCD flag-poll round-trips.

__device__ __forceinline__ float softplusf(float x) {
    return (x > 20.0f) ? x : log1pf(__expf(x));
}

__global__ __launch_bounds__(256) void detloss_fused(
    const float* __restrict__ cls0, const float* __restrict__ reg0, const float* __restrict__ obj0,
    const float* __restrict__ cls1, const float* __restrict__ reg1, const float* __restrict__ obj1,
    const float* __restrict__ cls2, const float* __restrict__ reg2, const float* __restrict__ obj2,
    const float* __restrict__ boxes, const int* __restrict__ labels,
    float* __restrict__ ws, float* __restrict__ out)
{
    const int bx = blockIdx.x;
    const int tid = threadIdx.x;
    const int wave = tid >> 6;
    const int lane = tid & 63;

    if (bx < OBJ_BLOCKS) {
        // ---- softplus(obj) reduction, float4-vectorized, shfl tree-reduced ----
        float a0 = 0.0f, a1 = 0.0f, a2 = 0.0f;
        const int gi = bx * 256 + tid;  // global float4 index, 33600 total
        if (gi < 33600) {
            const float4* p; int li;
            if (gi < 25600)      { p = (const float4*)obj0; li = gi; }
            else if (gi < 32000) { p = (const float4*)obj1; li = gi - 25600; }
            else                 { p = (const float4*)obj2; li = gi - 32000; }
            const float4 v = p[li];
            const float s = softplusf(v.x) + softplusf(v.y) + softplusf(v.z) + softplusf(v.w);
            if (gi < 25600) a0 = s; else if (gi < 32000) a1 = s; else a2 = s;
        }
        #pragma unroll
        for (int m = 32; m > 0; m >>= 1) {
            a0 += __shfl_xor(a0, m);
            a1 += __shfl_xor(a1, m);
            a2 += __shfl_xor(a2, m);
        }
        __shared__ float red[4][3];
        if (lane == 0) { red[wave][0] = a0; red[wave][1] = a1; red[wave][2] = a2; }
        __syncthreads();
        if (tid < 3) {
            const float v = red[0][tid] + red[1][tid] + red[2][tid] + red[3][tid];
            atomicAdd(&ws[tid * 5 + 0], v);
        }
    } else {
        // ---- positive-cell losses: one wave per (scale,batch), one lane per box ----
        const int task  = (bx - OBJ_BLOCKS) * 4 + wave;  // 0..47
        const int scale = task >> 4;
        const int batch = task & 15;
        const float* cls; const float* reg; const float* obj; int H, W;
        if (scale == 0)      { cls = cls0; reg = reg0; obj = obj0; H = 80; W = 80; }
        else if (scale == 1) { cls = cls1; reg = reg1; obj = obj1; H = 40; W = 40; }
        else                 { cls = cls2; reg = reg2; obj = obj2; H = 20; W = 20; }
        const int HW = H * W;

        const int j = batch * 64 + lane;                 // global box id
        const float4 bv = ((const float4*)boxes)[j];     // cx,cy,w,h
        const int lab = labels[j];
        int gx = (int)(bv.x * (float)W); gx = max(0, min(W - 1, gx));
        int gy = (int)(bv.y * (float)H); gy = max(0, min(H - 1, gy));
        const int cell = gy * W + gx;

        // winner = no later box (same batch) maps to same cell (scatter last-write-wins)
        // minlab = min label among boxes sharing the cell (argmax ties -> lowest idx)
        bool winner = true;
        int minlab = 1 << 30;
        for (int m = 0; m < 64; ++m) {
            const int oc = __shfl(cell, m);
            const int ol = __shfl(lab, m);
            if (oc == cell) {
                if (m > lane) winner = false;
                minlab = min(minlab, ol);
            }
        }

        float ce = 0.0f, sl = 0.0f, npos = 0.0f, po = 0.0f;
        if (winner) {
            // cross-entropy via 30 strided logits kept in registers (static unroll)
            const float* cb = cls + (size_t)batch * NCLS * HW + cell;
            float v[NCLS];
            float mx = -INFINITY;
            #pragma unroll
            for (int c = 0; c < NCLS; ++c) { v[c] = cb[(size_t)c * HW]; mx = fmaxf(mx, v[c]); }
            float se = 0.0f, tgt = 0.0f;
            #pragma unroll
            for (int c = 0; c < NCLS; ++c) {
                se += __expf(v[c] - mx);
                if (c == minlab) tgt = v[c];   // cndmask, minlab known pre-gather
            }
            ce = mx + __logf(se) - tgt;

            // smooth-L1 (beta=1) vs own box (last-write target), mean/4, clamp 10
            const float* rb = reg + (size_t)batch * 4 * HW + cell;
            const float t[4] = { bv.x, bv.y, bv.z, bv.w };
            #pragma unroll
            for (int k = 0; k < 4; ++k) {
                const float d = fabsf(rb[(size_t)k * HW] - t[k]);
                sl += (d < 1.0f) ? 0.5f * d * d : (d - 0.5f);
            }
            sl = fminf(sl * 0.25f, 10.0f);

            po = obj[(size_t)batch * HW + cell];
            npos = 1.0f;
        }
        #pragma unroll
        for (int m = 32; m > 0; m >>= 1) {
            ce   += __shfl_xor(ce, m);
            sl   += __shfl_xor(sl, m);
            npos += __shfl_xor(npos, m);
            po   += __shfl_xor(po, m);
        }
        if (lane == 0) {
            atomicAdd(&ws[scale * 5 + 1], ce);
            atomicAdd(&ws[scale * 5 + 2], sl);
            atomicAdd(&ws[scale * 5 + 3], npos);
            atomicAdd(&ws[scale * 5 + 4], po);
        }
        __syncthreads();  // pos blocks: all waves' atomics issued before counter bump
    }

    // ---- last-block-done finalize (single kernel, no second launch) ----
    if (bx < OBJ_BLOCKS) __syncthreads();   // obj blocks: atomics by tid<3 done
    if (tid == 0) {
        __threadfence();  // release: fp accumulator atomics visible before counter
        unsigned* ctr = (unsigned*)ws + 15;
        const unsigned old = atomicAdd(ctr, 1u);
        if (old == TOTAL_BLOCKS - 1) {
            __threadfence();  // acquire
            float f[15];
            #pragma unroll
            for (int k = 0; k < 15; ++k)
                f[k] = __hip_atomic_load(&ws[k], __ATOMIC_RELAXED, __HIP_MEMORY_SCOPE_AGENT);
            const float Ms[3] = { 16.0f * 6400.0f, 16.0f * 1600.0f, 16.0f * 400.0f };
            float clsl = 0.0f, regl = 0.0f, objl = 0.0f;
            #pragma unroll
            for (int s = 0; s < 3; ++s) {
                const float npos = fmaxf(f[s * 5 + 3], 1.0f);
                clsl += f[s * 5 + 1] / npos;                   // CLS_W = 1
                regl += 5.0f * f[s * 5 + 2] / npos;            // REG_W = 5
                objl += (f[s * 5 + 0] - f[s * 5 + 4]) / Ms[s]; // OBJ_W = 1
            }
            clsl /= 3.0f; regl /= 3.0f; objl /= 3.0f;
            out[0] = clsl + regl + objl;
            out[1] = clsl;
            out[2] = regl;
            out[3] = objl;
        }
    }
}

extern "C" void kernel_launch(void* const* d_in, const int* in_sizes, int n_in,
                              void* d_out, int out_size, void* d_ws, size_t ws_size,
                              hipStream_t stream) {
    const float* cls0   = (const float*)d_in[0];
    const float* reg0   = (const float*)d_in[1];
    const float* obj0   = (const float*)d_in[2];
    const float* cls1   = (const float*)d_in[3];
    const float* reg1   = (const float*)d_in[4];
    const float* obj1   = (const float*)d_in[5];
    const float* cls2   = (const float*)d_in[6];
    const float* reg2   = (const float*)d_in[7];
    const float* obj2   = (const float*)d_in[8];
    const float* boxes  = (const float*)d_in[9];
    const int*   labels = (const int*)d_in[10];
    float* ws  = (float*)d_ws;
    float* out = (float*)d_out;

    hipMemsetAsync(ws, 0, 64, stream);  // zero 15 fp accumulators + counter

    detloss_fused<<<dim3(TOTAL_BLOCKS), 256, 0, stream>>>(
        cls0, reg0, obj0, cls1, reg1, obj1, cls2, reg2, obj2,
        boxes, labels, ws, out);
}